// Round 3
// baseline (95.488 us; speedup 1.0000x reference)
//
#include <hip/hip_runtime.h>
#include <cstddef>

#define NDET 32
#define ME   128   // max electrons (n_e)
#define MN   128   // nuclei
#define EBLK 8     // electrons per block
#define NOUT (NDET * ME)   // 4096 orbital columns
#define LOG2E 1.4426950408889634f

#if __has_builtin(__builtin_amdgcn_exp2f)
#define EXP2(x) __builtin_amdgcn_exp2f(x)
#else
#define EXP2(x) exp2f(x)
#endif

typedef float v2f __attribute__((ext_vector_type(2)));

__device__ __forceinline__ float rdlane(float v, int lane) {
    return __uint_as_float(__builtin_amdgcn_readlane(__float_as_uint(v), lane));
}

// One block: fixed (spin s, det d), 8 electrons, all 128 j.
// 512 threads: j = tid&127, g = tid>>7 in [0,4) picks a 32-nucleus quarter.
//
// Bottleneck analysis (R2): kernel was LDS-return-bandwidth bound — 3
// broadcast ds_read_b128/iter write 3 KB to register files = 24 cyc/iter
// at 128 B/cyc, above the 64-cyc/iter trans-pipe floor aggregated per CU.
// Fix: the wave-uniform du table lives in per-lane REGISTERS (lane l holds
// du[n=l&31][4*(l>>5)+k]); the fully-unrolled loop pulls each value with
// v_readlane (compile-time lane index -> SGPR operand), leaving only one
// broadcast ds_read_b128 (feats) per iter = 8 LDS cyc. Mean-centering is
// folded into a per-thread constant negC = -(m.w) so the centering pass
// and one barrier disappear. duv stores -dist*log2e (negate pre-folded).
__global__ __launch_bounds__(512, 8) void env_kernel(
    const float* __restrict__ up_coords,
    const float* __restrict__ down_coords,
    const float* __restrict__ nuc_coords,
    const float* __restrict__ nuc_charges,
    const float* __restrict__ W_pi_up,
    const float* __restrict__ W_zeta_up,
    const float* __restrict__ W_pi_down,
    const float* __restrict__ W_zeta_down,
    float* __restrict__ out)
{
    __shared__ float4 feats4[MN];              // 2 KB: raw (charge, x, y, z)
    __shared__ __align__(16) float duv[MN * EBLK];  // 4 KB: [n][8 e]: -dist*log2e
    __shared__ float  ecl[EBLK * 3];           // this block's electron coords
    __shared__ float  msum[2][3];              // per-wave partial coord sums
    __shared__ float4 red[3][128][2];          // 12 KB: partials from quarters 1..3

    const int tid = (int)threadIdx.x;
    const int e0  = (int)blockIdx.x * EBLK;
    const int d   = (int)blockIdx.y;
    const int s   = (int)blockIdx.z;

    const float* ec = s ? down_coords : up_coords;
    const float* We = s ? W_pi_down   : W_pi_up;    // exponent factors (zeta = feats@W_pi)
    const float* Ww = s ? W_zeta_down : W_zeta_up;  // nuclear weights  (pi   = feats@W_zeta)

    // Phase 1: stage raw nuclear data + this block's electron coords.
    if (tid < MN) {
        feats4[tid] = make_float4(nuc_charges[tid],
                                  nuc_coords[tid * 3 + 0],
                                  nuc_coords[tid * 3 + 1],
                                  nuc_coords[tid * 3 + 2]);
    } else if (tid < MN + EBLK * 3) {
        ecl[tid - MN] = ec[e0 * 3 + (tid - MN)];
    }
    __syncthreads();

    // Phase 2a: mean of nuclear coords via shuffle butterfly on waves 0,1.
    if (tid < MN) {
        float4 f = feats4[tid];
        float sx = f.y, sy = f.z, sz = f.w;
        #pragma unroll
        for (int off = 32; off > 0; off >>= 1) {
            sx += __shfl_xor(sx, off);
            sy += __shfl_xor(sy, off);
            sz += __shfl_xor(sz, off);
        }
        if ((tid & 63) == 0) {
            const int w = tid >> 6;
            msum[w][0] = sx; msum[w][1] = sy; msum[w][2] = sz;
        }
    }

    // Phase 2b (same region: reads only phase-1 LDS): du table, negated,
    // log2e-scaled. Thread t: n = t>>2, pair q = t&3.
    {
        const int n = tid >> 2;
        const int q = tid & 3;
        const float4 f = feats4[n];   // raw nucleus coords
        float r[2];
        #pragma unroll
        for (int i = 0; i < 2; ++i) {
            const int e = q * 2 + i;
            const float dx = ecl[e * 3 + 0] - f.y;
            const float dy = ecl[e * 3 + 1] - f.z;
            const float dz = ecl[e * 3 + 2] - f.w;
            r[i] = sqrtf(fmaf(dx, dx, fmaf(dy, dy, dz * dz))) * (-LOG2E);
        }
        *(float2*)&duv[n * EBLK + q * 2] = make_float2(r[0], r[1]);
    }
    __syncthreads();

    const float mx = (msum[0][0] + msum[1][0]) * (1.f / MN);
    const float my = (msum[0][1] + msum[1][1]) * (1.f / MN);
    const float mz = (msum[0][2] + msum[1][2]) * (1.f / MN);

    const int j = tid & 127;
    const int g = tid >> 7;          // wave-uniform quarter
    const int o = d * ME + j;
    const int nbeg = g * 32;

    // Packed weights: .x -> zeta path (W_pi), .y -> pi path (W_zeta).
    const v2f w0 = { We[0*NOUT+o], Ww[0*NOUT+o] };
    const v2f w1 = { We[1*NOUT+o], Ww[1*NOUT+o] };
    const v2f w2 = { We[2*NOUT+o], Ww[2*NOUT+o] };
    const v2f w3 = { We[3*NOUT+o], Ww[3*NOUT+o] };
    // Centering folded: zeta/pi = f_raw.w0..w3 - (mx*w1+my*w2+mz*w3)
    const v2f negC = -(mx * w1 + (my * w2 + mz * w3));

    // Wave-register copy of this quarter's du sub-table:
    // lane l holds du[nbeg + (l&31)][4*(l>>5) + k], k = 0..3.
    const int lane = tid & 63;
    const float4 dq = *(const float4*)&duv[(nbeg + (lane & 31)) * EBLK + (lane >> 5) * 4];
    const float dr[4] = { dq.x, dq.y, dq.z, dq.w };

    float acc[EBLK] = {0.f, 0.f, 0.f, 0.f, 0.f, 0.f, 0.f, 0.f};

    #pragma unroll
    for (int nl = 0; nl < 32; ++nl) {
        const float4 f = feats4[nbeg + nl];                           // only LDS read in loop
        // zp.x = zeta, zp.y = pi  (4 x v_pk_fma_f32)
        v2f zp = f.x * w0 + (f.y * w1 + (f.z * w2 + (f.w * w3 + negC)));
        const float az = __builtin_fabsf(zp.x);
        const float pi = zp.y;
        #pragma unroll
        for (int e = 0; e < EBLK; ++e) {
            // du from wave registers: SGPR via readlane (compile-time lane).
            const float du = rdlane(dr[e & 3], (e >> 2) * 32 + nl);
            const float t  = EXP2(du * az);    // du pre-negated & log2e-scaled
            acc[e] = fmaf(pi, t, acc[e]);
        }
    }

    // Quarters 1..3 dump partials; quarter 0 reduces and stores.
    __syncthreads();
    if (g) {
        red[g - 1][j][0] = make_float4(acc[0], acc[1], acc[2], acc[3]);
        red[g - 1][j][1] = make_float4(acc[4], acc[5], acc[6], acc[7]);
    }
    __syncthreads();
    if (!g) {
        float4 p0 = red[0][j][0], p1 = red[0][j][1];
        const float4 q0 = red[1][j][0], q1 = red[1][j][1];
        const float4 r0 = red[2][j][0], r1 = red[2][j][1];
        p0.x += q0.x + r0.x; p0.y += q0.y + r0.y;
        p0.z += q0.z + r0.z; p0.w += q0.w + r0.w;
        p1.x += q1.x + r1.x; p1.y += q1.y + r1.y;
        p1.z += q1.z + r1.z; p1.w += q1.w + r1.w;
        // out[s][d][e][j], e = e0 + i
        float* op = out + ((((size_t)s * NDET + d) * ME + e0) * ME + j);
        op[0 * ME] = acc[0] + p0.x;
        op[1 * ME] = acc[1] + p0.y;
        op[2 * ME] = acc[2] + p0.z;
        op[3 * ME] = acc[3] + p0.w;
        op[4 * ME] = acc[4] + p1.x;
        op[5 * ME] = acc[5] + p1.y;
        op[6 * ME] = acc[6] + p1.z;
        op[7 * ME] = acc[7] + p1.w;
    }
}

extern "C" void kernel_launch(void* const* d_in, const int* in_sizes, int n_in,
                              void* d_out, int out_size, void* d_ws, size_t ws_size,
                              hipStream_t stream)
{
    (void)in_sizes; (void)n_in; (void)out_size; (void)d_ws; (void)ws_size;
    env_kernel<<<dim3(ME / EBLK, NDET, 2), 512, 0, stream>>>(
        (const float*)d_in[0],   // up_coords
        (const float*)d_in[1],   // down_coords
        (const float*)d_in[2],   // nuc_coords
        (const float*)d_in[3],   // nuc_charges
        (const float*)d_in[4],   // W_pi_up
        (const float*)d_in[5],   // W_zeta_up
        (const float*)d_in[6],   // W_pi_down
        (const float*)d_in[7],   // W_zeta_down
        (float*)d_out);
}

// Round 4
// 90.284 us; speedup vs baseline: 1.0576x; 1.0576x over previous
//
#include <hip/hip_runtime.h>
#include <cstddef>

#define NDET 32
#define ME   128   // max electrons (n_e)
#define MN   128   // nuclei
#define EBLK 16    // electrons per block
#define NOUT (NDET * ME)   // 4096 orbital columns
#define LOG2E 1.4426950408889634f

#if __has_builtin(__builtin_amdgcn_exp2f)
#define EXP2(x) __builtin_amdgcn_exp2f(x)
#else
#define EXP2(x) exp2f(x)
#endif

typedef float v2f __attribute__((ext_vector_type(2)));

// One block: fixed (spin s, det d), 16 electrons, all 128 j.
// 512 threads: j = tid&127, g = tid>>7 in [0,4) picks a 32-nucleus quarter.
//
// Machine model (confirmed R1-R3): v_exp_f32 (quarter-rate, 8 cyc/wave) and
// regular VALU serialize on the same SIMD issue port — no cross-wave
// trans/VALU overlap. Kernel time ~= sum(VALU) + sum(trans). Trans work is
// fixed (2048 wave-exps/SIMD = 16.4k cyc), so the only lever is VALU cycles
// per exp. EBLK=16 amortizes the (zeta,pi) packed dot-chain (5 instrs) over
// 16 exps: per iter = 5 + 8 pk_mul + 8 pk_fma = 21 VALU instrs (42 cyc)
// + 16 exp (128 cyc) -> 2.6 VALU cyc/exp, the structural minimum (1 packed
// mul + 1 packed fma per exp pair is irreducible). du table is broadcast
// ds_read_b128 (cheap, co-issues on lgkm pipe — R3 disproved the LDS-BW
// theory); duv stores -dist*log2e so the negate is pre-folded; the nuclear
// mean-centering is folded into negC = -(m.w) per thread.
__global__ __launch_bounds__(512, 4) void env_kernel(
    const float* __restrict__ up_coords,
    const float* __restrict__ down_coords,
    const float* __restrict__ nuc_coords,
    const float* __restrict__ nuc_charges,
    const float* __restrict__ W_pi_up,
    const float* __restrict__ W_zeta_up,
    const float* __restrict__ W_pi_down,
    const float* __restrict__ W_zeta_down,
    float* __restrict__ out)
{
    __shared__ float4 feats4[MN];                   // 2 KB: raw (charge, x, y, z)
    __shared__ __align__(16) float duv[MN * EBLK];  // 8 KB: [n][16 e]: -dist*log2e
    __shared__ float  ecl[EBLK * 3];                // this block's electron coords
    __shared__ float  msum[2][3];                   // per-wave partial coord sums
    __shared__ float4 red[3][128][4];               // 24 KB: partials from quarters 1..3

    const int tid = (int)threadIdx.x;
    const int e0  = (int)blockIdx.x * EBLK;
    const int d   = (int)blockIdx.y;
    const int s   = (int)blockIdx.z;

    const float* ec = s ? down_coords : up_coords;
    const float* We = s ? W_pi_down   : W_pi_up;    // exponent factors (zeta = feats@W_pi)
    const float* Ww = s ? W_zeta_down : W_zeta_up;  // nuclear weights  (pi   = feats@W_zeta)

    // Phase 1: stage raw nuclear data + this block's electron coords.
    if (tid < MN) {
        feats4[tid] = make_float4(nuc_charges[tid],
                                  nuc_coords[tid * 3 + 0],
                                  nuc_coords[tid * 3 + 1],
                                  nuc_coords[tid * 3 + 2]);
    } else if (tid < MN + EBLK * 3) {
        ecl[tid - MN] = ec[e0 * 3 + (tid - MN)];
    }
    __syncthreads();

    // Phase 2a: mean of nuclear coords via shuffle butterfly on waves 0,1.
    if (tid < MN) {
        float4 f = feats4[tid];
        float sx = f.y, sy = f.z, sz = f.w;
        #pragma unroll
        for (int off = 32; off > 0; off >>= 1) {
            sx += __shfl_xor(sx, off);
            sy += __shfl_xor(sy, off);
            sz += __shfl_xor(sz, off);
        }
        if ((tid & 63) == 0) {
            const int w = tid >> 6;
            msum[w][0] = sx; msum[w][1] = sy; msum[w][2] = sz;
        }
    }

    // Phase 2b (same region, reads only phase-1 LDS): du table, negated,
    // log2e-scaled. Thread t: n = t>>2, quarter q = t&3 -> electrons 4q..4q+3.
    {
        const int n = tid >> 2;
        const int q = tid & 3;
        const float4 f = feats4[n];   // raw nucleus coords
        float r[4];
        #pragma unroll
        for (int i = 0; i < 4; ++i) {
            const int e = q * 4 + i;
            const float dx = ecl[e * 3 + 0] - f.y;
            const float dy = ecl[e * 3 + 1] - f.z;
            const float dz = ecl[e * 3 + 2] - f.w;
            r[i] = sqrtf(fmaf(dx, dx, fmaf(dy, dy, dz * dz))) * (-LOG2E);
        }
        *(float4*)&duv[n * EBLK + q * 4] = make_float4(r[0], r[1], r[2], r[3]);
    }
    __syncthreads();

    const float mx = (msum[0][0] + msum[1][0]) * (1.f / MN);
    const float my = (msum[0][1] + msum[1][1]) * (1.f / MN);
    const float mz = (msum[0][2] + msum[1][2]) * (1.f / MN);

    const int j = tid & 127;
    const int g = tid >> 7;          // wave-uniform quarter
    const int o = d * ME + j;
    const int nbeg = g * 32;

    // Packed weights: .x -> zeta path (W_pi), .y -> pi path (W_zeta).
    const v2f w0 = { We[0*NOUT+o], Ww[0*NOUT+o] };
    const v2f w1 = { We[1*NOUT+o], Ww[1*NOUT+o] };
    const v2f w2 = { We[2*NOUT+o], Ww[2*NOUT+o] };
    const v2f w3 = { We[3*NOUT+o], Ww[3*NOUT+o] };
    // Centering folded: zeta/pi = f_raw.w0..w3 - (mx*w1+my*w2+mz*w3)
    const v2f negC = -(mx * w1 + (my * w2 + mz * w3));

    v2f acc[8];
    #pragma unroll
    for (int k = 0; k < 8; ++k) acc[k] = (v2f){0.f, 0.f};

    const float4* du4 = (const float4*)duv;
    #pragma unroll 4
    for (int n = nbeg; n < nbeg + 32; ++n) {
        const float4 f = feats4[n];                                   // LDS broadcast
        // zp.x = zeta, zp.y = pi  (4 x v_pk_fma_f32)
        v2f zp = f.x * w0 + (f.y * w1 + (f.z * w2 + (f.w * w3 + negC)));
        const float az = __builtin_fabsf(zp.x);
        const v2f az2 = {az, az};
        const v2f pi2 = {zp.y, zp.y};
        const float4 u0 = du4[n * 4 + 0];                             // LDS broadcast
        const float4 u1 = du4[n * 4 + 1];
        const float4 u2 = du4[n * 4 + 2];
        const float4 u3 = du4[n * 4 + 3];
        v2f t0 = (v2f){u0.x, u0.y} * az2;   // du already negated & log2e-scaled
        v2f t1 = (v2f){u0.z, u0.w} * az2;
        v2f t2 = (v2f){u1.x, u1.y} * az2;
        v2f t3 = (v2f){u1.z, u1.w} * az2;
        v2f t4 = (v2f){u2.x, u2.y} * az2;
        v2f t5 = (v2f){u2.z, u2.w} * az2;
        v2f t6 = (v2f){u3.x, u3.y} * az2;
        v2f t7 = (v2f){u3.z, u3.w} * az2;
        t0.x = EXP2(t0.x); t0.y = EXP2(t0.y);
        t1.x = EXP2(t1.x); t1.y = EXP2(t1.y);
        t2.x = EXP2(t2.x); t2.y = EXP2(t2.y);
        t3.x = EXP2(t3.x); t3.y = EXP2(t3.y);
        t4.x = EXP2(t4.x); t4.y = EXP2(t4.y);
        t5.x = EXP2(t5.x); t5.y = EXP2(t5.y);
        t6.x = EXP2(t6.x); t6.y = EXP2(t6.y);
        t7.x = EXP2(t7.x); t7.y = EXP2(t7.y);
        acc[0] = acc[0] + pi2 * t0;
        acc[1] = acc[1] + pi2 * t1;
        acc[2] = acc[2] + pi2 * t2;
        acc[3] = acc[3] + pi2 * t3;
        acc[4] = acc[4] + pi2 * t4;
        acc[5] = acc[5] + pi2 * t5;
        acc[6] = acc[6] + pi2 * t6;
        acc[7] = acc[7] + pi2 * t7;
    }

    // Quarters 1..3 dump partials; quarter 0 reduces and stores.
    if (g) {
        #pragma unroll
        for (int k = 0; k < 4; ++k)
            red[g - 1][j][k] = make_float4(acc[2*k].x, acc[2*k].y,
                                           acc[2*k+1].x, acc[2*k+1].y);
    }
    __syncthreads();
    if (!g) {
        float r[EBLK];
        #pragma unroll
        for (int k = 0; k < 8; ++k) { r[2*k] = acc[k].x; r[2*k+1] = acc[k].y; }
        #pragma unroll
        for (int q = 0; q < 3; ++q) {
            #pragma unroll
            for (int k = 0; k < 4; ++k) {
                const float4 p = red[q][j][k];
                r[4*k + 0] += p.x; r[4*k + 1] += p.y;
                r[4*k + 2] += p.z; r[4*k + 3] += p.w;
            }
        }
        // out[s][d][e][j], e = e0 + i
        float* op = out + ((((size_t)s * NDET + d) * ME + e0) * ME + j);
        #pragma unroll
        for (int e = 0; e < EBLK; ++e) op[e * ME] = r[e];
    }
}

extern "C" void kernel_launch(void* const* d_in, const int* in_sizes, int n_in,
                              void* d_out, int out_size, void* d_ws, size_t ws_size,
                              hipStream_t stream)
{
    (void)in_sizes; (void)n_in; (void)out_size; (void)d_ws; (void)ws_size;
    env_kernel<<<dim3(ME / EBLK, NDET, 2), 512, 0, stream>>>(
        (const float*)d_in[0],   // up_coords
        (const float*)d_in[1],   // down_coords
        (const float*)d_in[2],   // nuc_coords
        (const float*)d_in[3],   // nuc_charges
        (const float*)d_in[4],   // W_pi_up
        (const float*)d_in[5],   // W_zeta_up
        (const float*)d_in[6],   // W_pi_down
        (const float*)d_in[7],   // W_zeta_down
        (float*)d_out);
}